// Round 9
// baseline (2444.468 us; speedup 1.0000x reference)
//
#include <hip/hip_runtime.h>
#include <hip/hip_bf16.h>
#include <math.h>

typedef __hip_bfloat16 bf16;

// Problem constants (fixed by reference)
#define B_      8
#define S_      2048
#define DIN     1024
#define DSTATE  1024
#define H_      16
#define DH_     64
#define PROJ4   4096   // 4*DSTATE

// Barrier that does NOT drain vmcnt: LDS ordering only.
#define BARRIER_LGKM() asm volatile("s_waitcnt lgkmcnt(0)\n\ts_barrier" ::: "memory")

// ---------------------------------------------------------------------------
// bf16 <-> f32 helpers (bit-level, RNE for store)
// ---------------------------------------------------------------------------
__device__ __forceinline__ unsigned short f2bf(float f) {
    unsigned int x = __float_as_uint(f);
    x += 0x7FFFu + ((x >> 16) & 1u);   // round-to-nearest-even
    return (unsigned short)(x >> 16);
}

__device__ __forceinline__ float4 load4(const float* p) { return *(const float4*)p; }
__device__ __forceinline__ float4 load4(const bf16* p) {
    uint2 u = *(const uint2*)p;    // 4 bf16 = 8 bytes
    float4 r;
    r.x = __uint_as_float((u.x & 0xFFFFu) << 16);
    r.y = __uint_as_float(u.x & 0xFFFF0000u);
    r.z = __uint_as_float((u.y & 0xFFFFu) << 16);
    r.w = __uint_as_float(u.y & 0xFFFF0000u);
    return r;
}
__device__ __forceinline__ void store4(float* p, float4 v) { *(float4*)p = v; }
__device__ __forceinline__ void store4(bf16* p, float4 v) {
    uint2 u;
    u.x = (unsigned int)f2bf(v.x) | ((unsigned int)f2bf(v.y) << 16);
    u.y = (unsigned int)f2bf(v.z) | ((unsigned int)f2bf(v.w) << 16);
    *(uint2*)p = u;
}

typedef __attribute__((ext_vector_type(8))) short bf16x8;
typedef __attribute__((ext_vector_type(4))) float f32x4;

// ---------------------------------------------------------------------------
// Prep kernels (~25us total): cast x f32->bf16 (RNE) and transpose-cast
// weights so GEMM B-operand is k-contiguous bf16 (R8: killed the 1.78e8
// LDS bank conflicts; GEMMs 570 -> ~300us).
// ---------------------------------------------------------------------------
__global__ __launch_bounds__(256) void cast_x_kernel(const float* __restrict__ src,
                                                     bf16* __restrict__ dst, int n8) {
    int i = blockIdx.x * 256 + threadIdx.x;
    if (i >= n8) return;
    const float* p = src + (size_t)i * 8;
    bf16* q = dst + (size_t)i * 8;
    store4(q, load4(p));
    store4(q + 4, load4(p + 4));
}

// src: f32 [R][C]  ->  dst: bf16 [C][R]   (64x64 LDS tiles)
__global__ __launch_bounds__(256) void transpose_cast_kernel(
        const float* __restrict__ src, bf16* __restrict__ dst, int R, int C) {
    __shared__ short t64[64][65];
    const int tid = threadIdx.x;
    const int r0 = blockIdx.y * 64;
    const int c0 = blockIdx.x * 64;
    const int rr = tid >> 4;           // 0..15
    const int c4 = (tid & 15) * 4;     // 0..60

    #pragma unroll
    for (int p = 0; p < 4; ++p) {
        int r = rr + p * 16;
        float4 v = load4(src + (size_t)(r0 + r) * C + c0 + c4);
        t64[r][c4 + 0] = (short)f2bf(v.x);
        t64[r][c4 + 1] = (short)f2bf(v.y);
        t64[r][c4 + 2] = (short)f2bf(v.z);
        t64[r][c4 + 3] = (short)f2bf(v.w);
    }
    __syncthreads();
    #pragma unroll
    for (int p = 0; p < 4; ++p) {
        int cc = rr + p * 16;          // output row = c0+cc
        unsigned int s0 = (unsigned short)t64[c4 + 0][cc] |
                          ((unsigned int)(unsigned short)t64[c4 + 1][cc] << 16);
        unsigned int s1 = (unsigned short)t64[c4 + 2][cc] |
                          ((unsigned int)(unsigned short)t64[c4 + 3][cc] << 16);
        uint2 u = make_uint2(s0, s1);
        *(uint2*)&dst[(size_t)(c0 + cc) * R + r0 + c4] = u;
    }
}

// ---------------------------------------------------------------------------
// MFMA bf16 GEMM, both operands bf16, B pre-transposed [N][K]: staging is
// pure 16B vector copies. 128x128 tile, BK=32, 4 waves. (R8, unchanged.)
// ---------------------------------------------------------------------------
template <typename TC>
__global__ __launch_bounds__(256) void gemm_bt(const bf16* __restrict__ A,
                                               const bf16* __restrict__ BT,
                                               TC* __restrict__ C,
                                               int N, int K, int lda, int ldb) {
    __shared__ short As[128 * 40];   // As[m][k], k contiguous
    __shared__ short Bs[128 * 40];   // Bs[n][k], k contiguous

    const int tid = threadIdx.x;
    const int m0 = blockIdx.y * 128;
    const int n0 = blockIdx.x * 128;

    const int row = tid >> 1;          // 0..127
    const int ks  = (tid & 1) * 16;    // 0 or 16

    const int wid = tid >> 6;
    const int wx = wid & 1, wy = wid >> 1;
    const int lane = tid & 63;
    const int c16 = lane & 15;
    const int quad = lane >> 4;

    const bf16* Ap = A + (size_t)(m0 + row) * lda + ks;
    const bf16* Bp = BT + (size_t)(n0 + row) * ldb + ks;

    f32x4 acc[4][4];
    #pragma unroll
    for (int i = 0; i < 4; ++i)
        #pragma unroll
        for (int j = 0; j < 4; ++j) acc[i][j] = (f32x4){0.f, 0.f, 0.f, 0.f};

    uint4 ra0 = *(const uint4*)Ap;
    uint4 ra1 = *(const uint4*)(Ap + 8);
    uint4 rb0 = *(const uint4*)Bp;
    uint4 rb1 = *(const uint4*)(Bp + 8);

    for (int k0 = 0; k0 < K; k0 += 32) {
        __syncthreads();
        *(uint4*)&As[row * 40 + ks]     = ra0;
        *(uint4*)&As[row * 40 + ks + 8] = ra1;
        *(uint4*)&Bs[row * 40 + ks]     = rb0;
        *(uint4*)&Bs[row * 40 + ks + 8] = rb1;
        __syncthreads();

        if (k0 + 32 < K) {
            ra0 = *(const uint4*)(Ap + k0 + 32);
            ra1 = *(const uint4*)(Ap + k0 + 40);
            rb0 = *(const uint4*)(Bp + k0 + 32);
            rb1 = *(const uint4*)(Bp + k0 + 40);
        }

        bf16x8 af[4], bfr[4];
        #pragma unroll
        for (int mt = 0; mt < 4; ++mt)
            af[mt] = *(const bf16x8*)&As[(wy * 64 + mt * 16 + c16) * 40 + quad * 8];
        #pragma unroll
        for (int nt = 0; nt < 4; ++nt)
            bfr[nt] = *(const bf16x8*)&Bs[(wx * 64 + nt * 16 + c16) * 40 + quad * 8];

        #pragma unroll
        for (int mt = 0; mt < 4; ++mt)
            #pragma unroll
            for (int nt = 0; nt < 4; ++nt)
                acc[mt][nt] = __builtin_amdgcn_mfma_f32_16x16x32_bf16(
                    af[mt], bfr[nt], acc[mt][nt], 0, 0, 0);
    }

    #pragma unroll
    for (int mt = 0; mt < 4; ++mt) {
        #pragma unroll
        for (int r = 0; r < 4; ++r) {
            int rowc = m0 + wy * 64 + mt * 16 + quad * 4 + r;
            TC* cp = C + (size_t)rowc * N + n0 + wx * 64;
            #pragma unroll
            for (int nt = 0; nt < 4; ++nt)
                cp[nt * 16 + c16] = (TC)acc[mt][nt][r];
        }
    }
}

// ---------------------------------------------------------------------------
// Recurrence v7: TWO chains per block, interleaved in one instruction stream.
//  R8 analysis: step = ~340cy VALU issue + ~1000cy stall (2 LDS round trips,
//  transcendental/FMA latency, barrier skew). Stall is latency, not thruput
//  -> hide it with an independent chain. Pair (b,h) and (b+4,h): SAME head
//  => shared weight registers (48/lane). Each STEP advances both chains with
//  the SAME two barriers: barrier+LDS cost per chain-step halves, and chain
//  B's issue fills chain A's stalls. Grid 64 blocks x 4 waves.
// ---------------------------------------------------------------------------
__device__ __forceinline__ float lane_bcast(float v, int lane) {
    return __int_as_float(__builtin_amdgcn_readlane(__float_as_int(v), lane));
}

#define RPT16(M) M(0) M(1) M(2) M(3) M(4) M(5) M(6) M(7) \
                 M(8) M(9) M(10) M(11) M(12) M(13) M(14) M(15)

__global__ __launch_bounds__(256, 1)
__attribute__((amdgpu_waves_per_eu(1, 2)))
void recur_kernel(bf16* __restrict__ proj, const float* __restrict__ sw) {
    const int tid = threadIdx.x;
    const int e = tid & 63;
    const int w = __builtin_amdgcn_readfirstlane(tid >> 6);   // 0..3
    const int d0 = w << 4;
    const int bid = blockIdx.x;             // 0..63
    const int b0 = bid >> 4;                // 0..3  (chain A batch)
    const int h = bid & 15;                 // shared head => shared weights

    __shared__ float2 part_rf[2][4][64];    // [chain][wave][e]
    __shared__ float  part_c[2][4][64];
    __shared__ char lds_force[56 * 1024];   // RA pressure-target relaxer (R5)
    asm volatile("" :: "v"((unsigned int)(size_t)lds_force));

    const float* Wc_p = sw + (size_t)h * 4096 + (size_t)d0 * 64 + e;
    const float* Wf_p = Wc_p + (size_t)16 * 4096;
    const float* Wr_p = Wc_p + (size_t)32 * 4096;

    #define DECLW(i) float wc##i, wf##i, wr##i;
    RPT16(DECLW)
    #undef DECLW
    #define LOADW(i) wc##i = Wc_p[(i) * 64]; \
                     wf##i = Wf_p[(i) * 64]; \
                     wr##i = Wr_p[(i) * 64];
    RPT16(LOADW)
    #undef LOADW
    #define PINW(i) asm volatile("" : "+v"(wc##i), "+v"(wf##i), "+v"(wr##i));
    RPT16(PINW)
    #undef PINW

    bf16* xiA = proj + (size_t)b0 * S_ * PROJ4 + h * 64 + e;        // chain A
    bf16* xiB = proj + (size_t)(b0 + 4) * S_ * PROJ4 + h * 64 + e;  // chain B

    f32x4 rxiA, rxfA, rxrA, rxiB, rxfB, rxrB;
    #define PRELOAD(U) { const bf16* p = xiA + (size_t)(U) * PROJ4; \
        rxiA[U] = __bfloat162float(p[0]); \
        rxfA[U] = __bfloat162float(p[1024]); \
        rxrA[U] = __bfloat162float(p[2048]); \
        const bf16* q = xiB + (size_t)(U) * PROJ4; \
        rxiB[U] = __bfloat162float(q[0]); \
        rxfB[U] = __bfloat162float(q[1024]); \
        rxrB[U] = __bfloat162float(q[2048]); }
    PRELOAD(0) PRELOAD(1) PRELOAD(2) PRELOAD(3)
    #undef PRELOAD

    float hA = 0.0f, hB = 0.0f;

    const bf16* ldA = xiA + (size_t)4 * PROJ4;
    bf16*       stA = xiA;
    const bf16* ldB = xiB + (size_t)4 * PROJ4;
    bf16*       stB = xiB;

    #define P1TA(i, X) { float hb = lane_bcast(hA, d0 + (i)); \
        aRA##X = fmaf(hb, wr##i, aRA##X); \
        aFA##X = fmaf(hb, wf##i, aFA##X); }
    #define P1TB(i, X) { float hb = lane_bcast(hB, d0 + (i)); \
        aRB##X = fmaf(hb, wr##i, aRB##X); \
        aFB##X = fmaf(hb, wf##i, aFB##X); }
    #define P2TA(i, X) { float qb = lane_bcast(rhA, d0 + (i)); \
        aCA##X = fmaf(qb, wc##i, aCA##X); }
    #define P2TB(i, X) { float qb = lane_bcast(rhB, d0 + (i)); \
        aCB##X = fmaf(qb, wc##i, aCB##X); }
    #define APPLY16(M) \
        M(0,0)  M(1,1)  M(2,0)  M(3,1)  M(4,0)  M(5,1)  M(6,0)  M(7,1) \
        M(8,0)  M(9,1)  M(10,0) M(11,1) M(12,0) M(13,1) M(14,0) M(15,1)

    #define STEP(U, REFILL) { \
        float xiA0 = rxiA[U], xfA0 = rxfA[U], xrA0 = rxrA[U]; \
        float xiB0 = rxiB[U], xfB0 = rxfB[U], xrB0 = rxrB[U]; \
        if (REFILL) { \
            const bf16* p = ldA + (size_t)(U) * PROJ4; \
            rxiA[U] = __bfloat162float(p[0]); \
            rxfA[U] = __bfloat162float(p[1024]); \
            rxrA[U] = __bfloat162float(p[2048]); \
            const bf16* q = ldB + (size_t)(U) * PROJ4; \
            rxiB[U] = __bfloat162float(q[0]); \
            rxfB[U] = __bfloat162float(q[1024]); \
            rxrB[U] = __bfloat162float(q[2048]); \
        } \
        float aRA0 = 0.f, aRA1 = 0.f, aFA0 = 0.f, aFA1 = 0.f; \
        float aRB0 = 0.f, aRB1 = 0.f, aFB0 = 0.f, aFB1 = 0.f; \
        APPLY16(P1TA) \
        APPLY16(P1TB) \
        part_rf[0][w][e] = make_float2(aRA0 + aRA1, aFA0 + aFA1); \
        part_rf[1][w][e] = make_float2(aRB0 + aRB1, aFB0 + aFB1); \
        BARRIER_LGKM(); \
        float2 a0 = part_rf[0][0][e], a1 = part_rf[0][1][e]; \
        float2 a2 = part_rf[0][2][e], a3 = part_rf[0][3][e]; \
        float2 b0v = part_rf[1][0][e], b1v = part_rf[1][1][e]; \
        float2 b2v = part_rf[1][2][e], b3v = part_rf[1][3][e]; \
        float srA = xrA0 + (a0.x + a1.x) + (a2.x + a3.x); \
        float sfA = xfA0 + (a0.y + a1.y) + (a2.y + a3.y); \
        float srB = xrB0 + (b0v.x + b1v.x) + (b2v.x + b3v.x); \
        float sfB = xfB0 + (b0v.y + b1v.y) + (b2v.y + b3v.y); \
        float rA = 1.f / (1.f + __expf(-srA)); \
        float fA = 1.f / (1.f + __expf(-sfA)); \
        float rB = 1.f / (1.f + __expf(-srB)); \
        float fB = 1.f / (1.f + __expf(-sfB)); \
        float rhA = rA * hA; \
        float rhB = rB * hB; \
        float aCA0 = 0.f, aCA1 = 0.f, aCB0 = 0.f, aCB1 = 0.f; \
        APPLY16(P2TA) \
        APPLY16(P2TB) \
        part_c[0][w][e] = aCA0 + aCA1; \
        part_c[1][w][e] = aCB0 + aCB1; \
        BARRIER_LGKM(); \
        float scA = xiA0 + (part_c[0][0][e] + part_c[0][1][e]) \
                         + (part_c[0][2][e] + part_c[0][3][e]); \
        float scB = xiB0 + (part_c[1][0][e] + part_c[1][1][e]) \
                         + (part_c[1][2][e] + part_c[1][3][e]); \
        scA = fminf(fmaxf(scA, -15.f), 15.f); \
        scB = fminf(fmaxf(scB, -15.f), 15.f); \
        float exA = __expf(-2.f * scA); \
        float exB = __expf(-2.f * scB); \
        float ccA = (1.f - exA) / (1.f + exA); \
        float ccB = (1.f - exB) / (1.f + exB); \
        hA = fA * hA + (1.f - fA) * ccA; \
        hB = fB * hB + (1.f - fB) * ccB; \
        if (w == (U)) { \
            stA[(size_t)(U) * PROJ4] = __float2bfloat16(hA); \
            stB[(size_t)(U) * PROJ4] = __float2bfloat16(hB); \
        } \
    }

    for (int t0 = 0; t0 < S_ - 4; t0 += 4) {
        STEP(0, 1) STEP(1, 1) STEP(2, 1) STEP(3, 1)
        ldA += (size_t)4 * PROJ4;
        stA += (size_t)4 * PROJ4;
        ldB += (size_t)4 * PROJ4;
        stB += (size_t)4 * PROJ4;
    }
    STEP(0, 0) STEP(1, 0) STEP(2, 0) STEP(3, 0)

    #undef STEP
    #undef P1TA
    #undef P1TB
    #undef P2TA
    #undef P2TB
    #undef APPLY16
}

// ---------------------------------------------------------------------------
// Gated RMSNorm in place over proj cols [0:1024).
// ---------------------------------------------------------------------------
__global__ __launch_bounds__(256) void gate_norm_kernel(bf16* __restrict__ proj,
                                                        const float* __restrict__ nw) {
    const int row = blockIdx.x;
    const int tid = threadIdx.x;
    __shared__ float red[4];

    bf16* hp = proj + (size_t)row * PROJ4;
    const bf16* gp = hp + 3 * DSTATE;

    float4 hv = load4(hp + tid * 4);
    float4 gv = load4(gp + tid * 4);

    float v0 = hv.x * (gv.x / (1.f + __expf(-gv.x)));
    float v1 = hv.y * (gv.y / (1.f + __expf(-gv.y)));
    float v2 = hv.z * (gv.z / (1.f + __expf(-gv.z)));
    float v3 = hv.w * (gv.w / (1.f + __expf(-gv.w)));

    float ss = v0 * v0 + v1 * v1 + v2 * v2 + v3 * v3;
    #pragma unroll
    for (int mask = 32; mask >= 1; mask >>= 1)
        ss += __shfl_xor(ss, mask, 64);

    const int wid = tid >> 6;
    if ((tid & 63) == 0) red[wid] = ss;
    __syncthreads();
    float tot = red[0] + red[1] + red[2] + red[3];
    float scale = rsqrtf(tot * (1.0f / (float)DSTATE) + 1e-6f);

    float4 nv = *(const float4*)(nw + tid * 4);
    float4 y;
    y.x = v0 * scale * nv.x;
    y.y = v1 * scale * nv.y;
    y.z = v2 * scale * nv.z;
    y.w = v3 * scale * nv.w;
    store4(hp + tid * 4, y);
}

// ---------------------------------------------------------------------------
extern "C" void kernel_launch(void* const* d_in, const int* in_sizes, int n_in,
                              void* d_out, int out_size, void* d_ws, size_t ws_size,
                              hipStream_t stream) {
    const float* x     = (const float*)d_in[0];   // [B,S,DIN]
    const float* w_in  = (const float*)d_in[1];   // [DIN, 4*DSTATE]
    const float* sw    = (const float*)d_in[2];   // [3H, DH, DH]
    const float* nw    = (const float*)d_in[3];   // [DSTATE]
    const float* w_out = (const float*)d_in[4];   // [DSTATE, DOUT]
    float* out = (float*)d_out;

    // Workspace layout (bytes):
    //   proj   [16384, 4096] bf16 : 134,217,728
    //   xb     [16384, 1024] bf16 :  33,554,432
    //   w_inT  [4096, 1024]  bf16 :   8,388,608
    //   w_outT [1024, 1024]  bf16 :   2,097,152    total ~178 MB
    char* ws = (char*)d_ws;
    bf16* proj   = (bf16*)ws;
    bf16* xb     = (bf16*)(ws + 134217728);
    bf16* w_inT  = (bf16*)(ws + 134217728 + 33554432);
    bf16* w_outT = (bf16*)(ws + 134217728 + 33554432 + 8388608);

    // 0) prep: cast x -> bf16; transpose-cast weights -> bf16 [N][K]
    cast_x_kernel<<<(B_ * S_ * DIN / 8 + 255) / 256, 256, 0, stream>>>(x, xb,
                                                                B_ * S_ * DIN / 8);
    transpose_cast_kernel<<<dim3(PROJ4 / 64, DIN / 64), 256, 0, stream>>>(
        w_in, w_inT, DIN, PROJ4);
    transpose_cast_kernel<<<dim3(DSTATE / 64, DSTATE / 64), 256, 0, stream>>>(
        w_out, w_outT, DSTATE, DSTATE);

    // 1) input projection: [16384,1024]bf16 @ [1024,4096] -> proj bf16
    gemm_bt<bf16><<<dim3(PROJ4 / 128, (B_ * S_) / 128), 256, 0, stream>>>(
        xb, w_inT, proj, PROJ4, DIN, DIN, DIN);

    // 2) sequential gated recurrence: 2 chains/block, shared weights
    recur_kernel<<<64, 256, 0, stream>>>(proj, sw);

    // 3) gate + rmsnorm in place
    gate_norm_kernel<<<B_ * S_, 256, 0, stream>>>(proj, nw);

    // 4) output projection: proj(bf16, lda=4096) @ [1024,1024] -> out f32
    gemm_bt<float><<<dim3(DSTATE / 128, (B_ * S_) / 128), 256, 0, stream>>>(
        proj, w_outT, out, DSTATE, DSTATE, PROJ4, DSTATE);
}

// Round 10
// 1680.964 us; speedup vs baseline: 1.4542x; 1.4542x over previous
//
#include <hip/hip_runtime.h>
#include <hip/hip_bf16.h>
#include <math.h>

typedef __hip_bfloat16 bf16;

// Problem constants (fixed by reference)
#define B_      8
#define S_      2048
#define DIN     1024
#define DSTATE  1024
#define H_      16
#define DH_     64
#define PROJ4   4096   // 4*DSTATE
#define NT1     4096   // GEMM1 tiles: 16 tchunks x (8 b x 32 n)
#define NU_GN   128    // gn units: (tc, b)
#define NT2     1024   // GEMM2 tiles: (tc, b, nt)

// Barrier that does NOT drain vmcnt: LDS ordering only.
#define BARRIER_LGKM() asm volatile("s_waitcnt lgkmcnt(0)\n\ts_barrier" ::: "memory")

// ---------------------------------------------------------------------------
// Pipeline flags (zeroed each launch).
// ---------------------------------------------------------------------------
__device__ int g_q1;        // GEMM1 tile queue
__device__ int g_q2;        // gn unit queue
__device__ int g_q3;        // GEMM2 tile queue
__device__ int g_rc[128];   // per-(b,tc) GEMM1 tiles done (32 = x ready)
__device__ int g_rd[128];   // per-(b,tc) recur chains done (16 = h ready)
__device__ int g_gn[128];   // per-(b,tc) gate-norm done

__global__ void zero_flags() {
    int i = threadIdx.x;
    if (i == 0) { g_q1 = 0; g_q2 = 0; g_q3 = 0; }
    if (i < 128) { g_rc[i] = 0; g_rd[i] = 0; g_gn[i] = 0; }
}

// ---------------------------------------------------------------------------
// bf16 <-> f32 helpers (bit-level, RNE for store)
// ---------------------------------------------------------------------------
__device__ __forceinline__ unsigned short f2bf(float f) {
    unsigned int x = __float_as_uint(f);
    x += 0x7FFFu + ((x >> 16) & 1u);   // round-to-nearest-even
    return (unsigned short)(x >> 16);
}

__device__ __forceinline__ float4 load4(const float* p) { return *(const float4*)p; }
__device__ __forceinline__ float4 load4(const bf16* p) {
    uint2 u = *(const uint2*)p;    // 4 bf16 = 8 bytes
    float4 r;
    r.x = __uint_as_float((u.x & 0xFFFFu) << 16);
    r.y = __uint_as_float(u.x & 0xFFFF0000u);
    r.z = __uint_as_float((u.y & 0xFFFFu) << 16);
    r.w = __uint_as_float(u.y & 0xFFFF0000u);
    return r;
}
__device__ __forceinline__ void store4(float* p, float4 v) { *(float4*)p = v; }
__device__ __forceinline__ void store4(bf16* p, float4 v) {
    uint2 u;
    u.x = (unsigned int)f2bf(v.x) | ((unsigned int)f2bf(v.y) << 16);
    u.y = (unsigned int)f2bf(v.z) | ((unsigned int)f2bf(v.w) << 16);
    *(uint2*)p = u;
}

typedef __attribute__((ext_vector_type(8))) short bf16x8;
typedef __attribute__((ext_vector_type(4))) float f32x4;

// ---------------------------------------------------------------------------
// Prep kernels (~30us): cast x -> bf16; transpose-cast weights -> bf16 [N][K]
// (R8: killed the staging bank conflicts; RNE-identical results).
// ---------------------------------------------------------------------------
__global__ __launch_bounds__(256) void cast_x_kernel(const float* __restrict__ src,
                                                     bf16* __restrict__ dst, int n8) {
    int i = blockIdx.x * 256 + threadIdx.x;
    if (i >= n8) return;
    const float* p = src + (size_t)i * 8;
    bf16* q = dst + (size_t)i * 8;
    store4(q, load4(p));
    store4(q + 4, load4(p + 4));
}

__global__ __launch_bounds__(256) void transpose_cast_kernel(
        const float* __restrict__ src, bf16* __restrict__ dst, int R, int C) {
    __shared__ short t64[64][65];
    const int tid = threadIdx.x;
    const int r0 = blockIdx.y * 64;
    const int c0 = blockIdx.x * 64;
    const int rr = tid >> 4;           // 0..15
    const int c4 = (tid & 15) * 4;     // 0..60

    #pragma unroll
    for (int p = 0; p < 4; ++p) {
        int r = rr + p * 16;
        float4 v = load4(src + (size_t)(r0 + r) * C + c0 + c4);
        t64[r][c4 + 0] = (short)f2bf(v.x);
        t64[r][c4 + 1] = (short)f2bf(v.y);
        t64[r][c4 + 2] = (short)f2bf(v.z);
        t64[r][c4 + 3] = (short)f2bf(v.w);
    }
    __syncthreads();
    #pragma unroll
    for (int p = 0; p < 4; ++p) {
        int cc = rr + p * 16;
        unsigned int s0 = (unsigned short)t64[c4 + 0][cc] |
                          ((unsigned int)(unsigned short)t64[c4 + 1][cc] << 16);
        unsigned int s1 = (unsigned short)t64[c4 + 2][cc] |
                          ((unsigned int)(unsigned short)t64[c4 + 3][cc] << 16);
        uint2 u = make_uint2(s0, s1);
        *(uint2*)&dst[(size_t)(c0 + cc) * R + r0 + c4] = u;
    }
}

// ---------------------------------------------------------------------------
// Fast GEMM tile (device fn): both operands bf16, B pre-transposed [N][K],
// pure 16B vector staging, 0 bank conflicts (R8's gemm_bt as a tile).
// ---------------------------------------------------------------------------
template <typename TC>
__device__ void gemm_bt_tile(const bf16* __restrict__ A,
                             const bf16* __restrict__ BT,
                             TC* __restrict__ C, int N, int K, int lda, int ldb,
                             int m0, int n0, short* As, short* Bs) {
    const int tid = threadIdx.x;
    const int row = tid >> 1;          // 0..127
    const int ks  = (tid & 1) * 16;    // 0 or 16
    const int wid = tid >> 6;
    const int wx = wid & 1, wy = wid >> 1;
    const int lane = tid & 63;
    const int c16 = lane & 15;
    const int quad = lane >> 4;

    const bf16* Ap = A + (size_t)(m0 + row) * lda + ks;
    const bf16* Bp = BT + (size_t)(n0 + row) * ldb + ks;

    f32x4 acc[4][4];
    #pragma unroll
    for (int i = 0; i < 4; ++i)
        #pragma unroll
        for (int j = 0; j < 4; ++j) acc[i][j] = (f32x4){0.f, 0.f, 0.f, 0.f};

    uint4 ra0 = *(const uint4*)Ap;
    uint4 ra1 = *(const uint4*)(Ap + 8);
    uint4 rb0 = *(const uint4*)Bp;
    uint4 rb1 = *(const uint4*)(Bp + 8);

    for (int k0 = 0; k0 < K; k0 += 32) {
        __syncthreads();
        *(uint4*)&As[row * 40 + ks]     = ra0;
        *(uint4*)&As[row * 40 + ks + 8] = ra1;
        *(uint4*)&Bs[row * 40 + ks]     = rb0;
        *(uint4*)&Bs[row * 40 + ks + 8] = rb1;
        __syncthreads();

        if (k0 + 32 < K) {
            ra0 = *(const uint4*)(Ap + k0 + 32);
            ra1 = *(const uint4*)(Ap + k0 + 40);
            rb0 = *(const uint4*)(Bp + k0 + 32);
            rb1 = *(const uint4*)(Bp + k0 + 40);
        }

        bf16x8 af[4], bfr[4];
        #pragma unroll
        for (int mt = 0; mt < 4; ++mt)
            af[mt] = *(const bf16x8*)&As[(wy * 64 + mt * 16 + c16) * 40 + quad * 8];
        #pragma unroll
        for (int nt = 0; nt < 4; ++nt)
            bfr[nt] = *(const bf16x8*)&Bs[(wx * 64 + nt * 16 + c16) * 40 + quad * 8];

        #pragma unroll
        for (int mt = 0; mt < 4; ++mt)
            #pragma unroll
            for (int nt = 0; nt < 4; ++nt)
                acc[mt][nt] = __builtin_amdgcn_mfma_f32_16x16x32_bf16(
                    af[mt], bfr[nt], acc[mt][nt], 0, 0, 0);
    }

    #pragma unroll
    for (int mt = 0; mt < 4; ++mt) {
        #pragma unroll
        for (int r = 0; r < 4; ++r) {
            int rowc = m0 + wy * 64 + mt * 16 + quad * 4 + r;
            TC* cp = C + (size_t)rowc * N + n0 + wx * 64;
            #pragma unroll
            for (int nt = 0; nt < 4; ++nt)
                cp[nt * 16 + c16] = (TC)acc[mt][nt][r];
        }
    }
}

// ---------------------------------------------------------------------------
// Gated RMSNorm, wave-parallel (R7, passed): each wave owns rows r%4==w.
// ---------------------------------------------------------------------------
__device__ void gn_unit(bf16* __restrict__ proj, const float* __restrict__ nw,
                        int rbase) {
    const int lane = threadIdx.x & 63;
    const int w = threadIdx.x >> 6;
    for (int r = w; r < 128; r += 4) {
        bf16* hp = proj + (size_t)(rbase + r) * PROJ4;
        const bf16* gp = hp + 3 * DSTATE;
        float v[16];
        float ss = 0.f;
        #pragma unroll
        for (int k = 0; k < 4; ++k) {
            float4 hh = load4(hp + lane * 4 + k * 256);
            float4 gg = load4(gp + lane * 4 + k * 256);
            float t0 = hh.x * (gg.x / (1.f + __expf(-gg.x)));
            float t1 = hh.y * (gg.y / (1.f + __expf(-gg.y)));
            float t2 = hh.z * (gg.z / (1.f + __expf(-gg.z)));
            float t3 = hh.w * (gg.w / (1.f + __expf(-gg.w)));
            v[k * 4 + 0] = t0; v[k * 4 + 1] = t1;
            v[k * 4 + 2] = t2; v[k * 4 + 3] = t3;
            ss += t0 * t0 + t1 * t1 + t2 * t2 + t3 * t3;
        }
        #pragma unroll
        for (int m = 32; m >= 1; m >>= 1) ss += __shfl_xor(ss, m, 64);
        float scale = rsqrtf(ss * (1.0f / (float)DSTATE) + 1e-6f);
        #pragma unroll
        for (int k = 0; k < 4; ++k) {
            float4 nv = *(const float4*)(nw + lane * 4 + k * 256);
            float4 y;
            y.x = v[k * 4 + 0] * scale * nv.x;
            y.y = v[k * 4 + 1] * scale * nv.y;
            y.z = v[k * 4 + 2] * scale * nv.z;
            y.w = v[k * 4 + 3] * scale * nv.w;
            store4(hp + lane * 4 + k * 256, y);
        }
    }
}

// ---------------------------------------------------------------------------
// GEMM2 tile-queue drain (workers after q2; recur blocks after chains).
// ---------------------------------------------------------------------------
__device__ void drain_q3(const bf16* __restrict__ proj,
                         const bf16* __restrict__ w_outT,
                         float* __restrict__ out,
                         short* As, short* Bs, int* taskp) {
    for (;;) {
        __syncthreads();
        if (threadIdx.x == 0) *taskp = atomicAdd(&g_q3, 1);
        __syncthreads();
        int id = *taskp;
        if (id >= NT2) break;
        int tc = id >> 6, rem = id & 63, bb = rem >> 3, nt = rem & 7;
        int mIdx = bb * 16 + tc;
        if (threadIdx.x == 0) {
            while (__hip_atomic_load(&g_gn[mIdx], __ATOMIC_RELAXED,
                                     __HIP_MEMORY_SCOPE_AGENT) < 1)
                __builtin_amdgcn_s_sleep(8);
        }
        __syncthreads();
        __threadfence();   // acquire
        gemm_bt_tile<float>(proj, w_outT, out, DSTATE, DSTATE, PROJ4, DSTATE,
                            mIdx * 128, nt * 128, As, Bs);
    }
}

// ---------------------------------------------------------------------------
// Fused pipeline, grid = EXACTLY 256 blocks (1/CU — R7's 384 oversubscribed
// and slowed the latency-critical recur CUs):
//  blocks 0..127  : recur chains (b,h), R5 step structure, 128-step chunks;
//                   wait g_rc[b*16+tc]==32, run chunk, flag g_rd; then help q3.
//  blocks 128..255: workers with the FAST gemm_bt tile (R6/R7's worker GEMM
//                   was the conversion-heavy conflicted tile — that was the
//                   throughput error). q1 -> q2 (gn) -> q3.
// Budget: 4096*~20us + gn + 1024*~20us ~ 103k us-block < 128 CU * 1152us.
// Cadence: 256 tiles*20/128 = 40us < 72us recur chunk. Deadlock-free
// (acyclic: q1 never waits; recur<-q1; q2<-recur; q3<-q2).
// 57KB LDS keeps the RA pressure target relaxed (R6: VGPR=100 >= 88 needed).
// ---------------------------------------------------------------------------
__device__ __forceinline__ float lane_bcast(float v, int lane) {
    return __int_as_float(__builtin_amdgcn_readlane(__float_as_int(v), lane));
}

#define RPT16(M) M(0) M(1) M(2) M(3) M(4) M(5) M(6) M(7) \
                 M(8) M(9) M(10) M(11) M(12) M(13) M(14) M(15)

__global__ __launch_bounds__(256) void fused_kernel(
        const bf16* __restrict__ xb, const bf16* __restrict__ w_inT,
        const float* __restrict__ sw, const float* __restrict__ nw,
        const bf16* __restrict__ w_outT, bf16* __restrict__ proj,
        float* __restrict__ out) {
    __shared__ __align__(16) char smem[57344];
    const int tid = threadIdx.x;
    const int bid = blockIdx.x;

    short* As   = (short*)smem;              // [128][40]
    short* Bs   = (short*)(smem + 10240);    // [128][40]
    int*  taskp = (int*)(smem + 20480);

    if (bid < 128) {
        // ------------------------- recur role -------------------------
        float2* prf = (float2*)smem;           // [4][64]
        float*  pc  = (float*)(smem + 2048);   // [4][64]
        int*    tp2 = (int*)(smem + 3072);

        const int e = tid & 63;
        const int w = __builtin_amdgcn_readfirstlane(tid >> 6);   // 0..3
        const int d0 = w << 4;
        const int b = bid >> 4;
        const int h = bid & 15;

        const float* Wc_p = sw + (size_t)h * 4096 + (size_t)d0 * 64 + e;
        const float* Wf_p = Wc_p + (size_t)16 * 4096;
        const float* Wr_p = Wc_p + (size_t)32 * 4096;

        #define DECLW(i) float wc##i, wf##i, wr##i;
        RPT16(DECLW)
        #undef DECLW
        #define LOADW(i) wc##i = Wc_p[(i) * 64]; \
                         wf##i = Wf_p[(i) * 64]; \
                         wr##i = Wr_p[(i) * 64];
        RPT16(LOADW)
        #undef LOADW
        #define PINW(i) asm volatile("" : "+v"(wc##i), "+v"(wf##i), "+v"(wr##i));
        RPT16(PINW)
        #undef PINW

        bf16* xi_p = proj + (size_t)b * S_ * PROJ4 + h * 64 + e;
        float hreg = 0.0f;

        #define P1T(i, A) { float hb = lane_bcast(hreg, d0 + (i)); \
            aR##A = fmaf(hb, wr##i, aR##A); \
            aF##A = fmaf(hb, wf##i, aF##A); }
        #define P2T(i, A) { float qb = lane_bcast(rh, d0 + (i)); \
            aC##A = fmaf(qb, wc##i, aC##A); }

        #define STEP(U, REFILL) { \
            float xi0 = rxi[U], xf0 = rxf[U], xr0 = rxr[U]; \
            if (REFILL) { \
                const bf16* p = ld + (size_t)(U) * PROJ4; \
                rxi[U] = __bfloat162float(p[0]); \
                rxf[U] = __bfloat162float(p[1024]); \
                rxr[U] = __bfloat162float(p[2048]); \
            } \
            float aR0 = 0.f, aR1 = 0.f, aF0 = 0.f, aF1 = 0.f; \
            P1T(0,0)  P1T(1,1)  P1T(2,0)  P1T(3,1) \
            P1T(4,0)  P1T(5,1)  P1T(6,0)  P1T(7,1) \
            P1T(8,0)  P1T(9,1)  P1T(10,0) P1T(11,1) \
            P1T(12,0) P1T(13,1) P1T(14,0) P1T(15,1) \
            prf[w * 64 + e] = make_float2(aR0 + aR1, aF0 + aF1); \
            BARRIER_LGKM(); \
            float2 p0 = prf[0 * 64 + e], p1 = prf[1 * 64 + e]; \
            float2 p2 = prf[2 * 64 + e], p3 = prf[3 * 64 + e]; \
            float sr = xr0 + (p0.x + p1.x) + (p2.x + p3.x); \
            float sf = xf0 + (p0.y + p1.y) + (p2.y + p3.y); \
            float r = 1.f / (1.f + __expf(-sr)); \
            float f = 1.f / (1.f + __expf(-sf)); \
            float rh = r * hreg; \
            float aC0 = 0.f, aC1 = 0.f; \
            P2T(0,0)  P2T(1,1)  P2T(2,0)  P2T(3,1) \
            P2T(4,0)  P2T(5,1)  P2T(6,0)  P2T(7,1) \
            P2T(8,0)  P2T(9,1)  P2T(10,0) P2T(11,1) \
            P2T(12,0) P2T(13,1) P2T(14,0) P2T(15,1) \
            pc[w * 64 + e] = aC0 + aC1; \
            BARRIER_LGKM(); \
            float sc = xi0 + (pc[0 * 64 + e] + pc[1 * 64 + e]) \
                           + (pc[2 * 64 + e] + pc[3 * 64 + e]); \
            sc = fminf(fmaxf(sc, -15.f), 15.f); \
            float ex = __expf(-2.f * sc); \
            float cc = (1.f - ex) / (1.f + ex); \
            hreg = f * hreg + (1.f - f) * cc; \
            if (w == (U)) st[(size_t)(U) * PROJ4] = __float2bfloat16(hreg); \
        }

        for (int tc = 0; tc < 16; ++tc) {
            const int mIdx = b * 16 + tc;
            if (tid == 0) {
                while (__hip_atomic_load(&g_rc[mIdx], __ATOMIC_RELAXED,
                                         __HIP_MEMORY_SCOPE_AGENT) < 32)
                    __builtin_amdgcn_s_sleep(8);
            }
            __syncthreads();
            __threadfence();   // acquire

            bf16* xrow = xi_p + (size_t)(tc * 128) * PROJ4;
            f32x4 rxi, rxf, rxr;
            #define PRELOAD(U) { const bf16* p = xrow + (size_t)(U) * PROJ4; \
                rxi[U] = __bfloat162float(p[0]); \
                rxf[U] = __bfloat162float(p[1024]); \
                rxr[U] = __bfloat162float(p[2048]); }
            PRELOAD(0) PRELOAD(1) PRELOAD(2) PRELOAD(3)
            #undef PRELOAD

            const bf16* ld = xrow + (size_t)4 * PROJ4;
            bf16*       st = xrow;

            for (int t0 = 0; t0 < 124; t0 += 4) {
                STEP(0, 1) STEP(1, 1) STEP(2, 1) STEP(3, 1)
                ld += (size_t)4 * PROJ4;
                st += (size_t)4 * PROJ4;
            }
            STEP(0, 0) STEP(1, 0) STEP(2, 0) STEP(3, 0)

            __syncthreads();   // drains vmcnt: chunk h-stores complete
            if (tid == 0) {
                __threadfence();                // release
                atomicAdd(&g_rd[mIdx], 1);
            }
        }
        #undef STEP
        #undef P1T
        #undef P2T

        // Help drain GEMM2 tail (smem reused; first loop-head sync protects).
        __syncthreads();
        drain_q3(proj, w_outT, out, As, Bs, taskp);
        (void)tp2;
    } else {
        // ------------------------- worker role -------------------------
        // q1: GEMM1 tiles (fast bt tile), tc-major. Never waits.
        for (;;) {
            __syncthreads();
            if (tid == 0) *taskp = atomicAdd(&g_q1, 1);
            __syncthreads();
            int id = *taskp;
            if (id >= NT1) break;
            int tc = id >> 8, rem = id & 255, bb = rem >> 5, n = rem & 31;
            int mIdx = bb * 16 + tc;
            gemm_bt_tile<bf16>(xb, w_inT, proj, PROJ4, DIN, DIN, DIN,
                               mIdx * 128, n * 128, As, Bs);
            __syncthreads();   // drains vmcnt: tile stores complete
            if (tid == 0) {
                __threadfence();                // release
                atomicAdd(&g_rc[mIdx], 1);
            }
        }

        // q2: gate-norm units, wait on recur.
        for (;;) {
            __syncthreads();
            if (tid == 0) *taskp = atomicAdd(&g_q2, 1);
            __syncthreads();
            int id = *taskp;
            if (id >= NU_GN) break;
            int tc = id >> 3, bb = id & 7;
            int mIdx = bb * 16 + tc;
            if (tid == 0) {
                while (__hip_atomic_load(&g_rd[mIdx], __ATOMIC_RELAXED,
                                         __HIP_MEMORY_SCOPE_AGENT) < 16)
                    __builtin_amdgcn_s_sleep(8);
            }
            __syncthreads();
            __threadfence();   // acquire
            gn_unit(proj, nw, mIdx * 128);
            __syncthreads();   // drains vmcnt
            if (tid == 0) {
                __threadfence();                // release
                atomicAdd(&g_gn[mIdx], 1);
            }
        }

        // q3: GEMM2 tiles, wait on gn.
        drain_q3(proj, w_outT, out, As, Bs, taskp);
    }
}

// ---------------------------------------------------------------------------
extern "C" void kernel_launch(void* const* d_in, const int* in_sizes, int n_in,
                              void* d_out, int out_size, void* d_ws, size_t ws_size,
                              hipStream_t stream) {
    const float* x     = (const float*)d_in[0];   // [B,S,DIN]
    const float* w_in  = (const float*)d_in[1];   // [DIN, 4*DSTATE]
    const float* sw    = (const float*)d_in[2];   // [3H, DH, DH]
    const float* nw    = (const float*)d_in[3];   // [DSTATE]
    const float* w_out = (const float*)d_in[4];   // [DSTATE, DOUT]
    float* out = (float*)d_out;

    // Workspace layout (bytes):
    //   proj   [16384, 4096] bf16 : 134,217,728
    //   xb     [16384, 1024] bf16 :  33,554,432
    //   w_inT  [4096, 1024]  bf16 :   8,388,608
    //   w_outT [1024, 1024]  bf16 :   2,097,152    total ~178 MB
    char* ws = (char*)d_ws;
    bf16* proj   = (bf16*)ws;
    bf16* xb     = (bf16*)(ws + 134217728);
    bf16* w_inT  = (bf16*)(ws + 134217728 + 33554432);
    bf16* w_outT = (bf16*)(ws + 134217728 + 33554432 + 8388608);

    // 0) prep: cast x -> bf16; transpose-cast weights; zero pipeline flags
    cast_x_kernel<<<(B_ * S_ * DIN / 8 + 255) / 256, 256, 0, stream>>>(x, xb,
                                                                B_ * S_ * DIN / 8);
    transpose_cast_kernel<<<dim3(PROJ4 / 64, DIN / 64), 256, 0, stream>>>(
        w_in, w_inT, DIN, PROJ4);
    transpose_cast_kernel<<<dim3(DSTATE / 64, DSTATE / 64), 256, 0, stream>>>(
        w_out, w_outT, DSTATE, DSTATE);
    zero_flags<<<1, 128, 0, stream>>>();

    // 1) fused pipeline: GEMM1 / recur / gate-norm / GEMM2 overlapped
    fused_kernel<<<256, 256, 0, stream>>>(xb, w_inT, sw, nw, w_outT, proj, out);
}